// Round 9
// baseline (222.375 us; speedup 1.0000x reference)
//
#include <hip/hip_runtime.h>
#include <hip/hip_bf16.h>

#define N_NODES 50000
#define KNB 16
#define FDIM 128
#define HDIM 128
#define ALPHA 0.3f
#define BN_EPS 1e-3f

typedef __bf16 v8bf __attribute__((ext_vector_type(8)));
typedef float v4f __attribute__((ext_vector_type(4)));
typedef unsigned short ushort_t;

__device__ __forceinline__ float blo(unsigned int u) {
    union { float f; unsigned int i; } x; x.i = u << 16; return x.f;
}
__device__ __forceinline__ float bhi(unsigned int u) {
    union { float f; unsigned int i; } x; x.i = u & 0xffff0000u; return x.f;
}

__device__ __forceinline__ unsigned short f2bf(float f) {
    union { float f; unsigned int u; } x;
    x.f = f;
    unsigned int r = x.u + 0x7fffu + ((x.u >> 16) & 1u);  // RNE
    return (unsigned short)(r >> 16);
}

// packed f32x2 -> bf16x2 (RNE)
__device__ __forceinline__ unsigned int pk2(float a, float b) {
    __hip_bfloat162 h = __float22bfloat162_rn(make_float2(a, b));
    union { __hip_bfloat162 h; unsigned int u; } r; r.h = h; return r.u;
}

__device__ __forceinline__ float lrelu(float x) { return x > 0.f ? x : ALPHA * x; }

__device__ __forceinline__ v8bf load8f(const float* p) {
    float4 A = ((const float4*)p)[0];
    float4 B = ((const float4*)p)[1];
    union { v8bf v; unsigned int u[4]; } r;
    r.u[0] = pk2(A.x, A.y); r.u[1] = pk2(A.z, A.w);
    r.u[2] = pk2(B.x, B.y); r.u[3] = pk2(B.z, B.w);
    return r.v;
}

// ---------------------------------------------------------------------------
// Kernel 0: convert + transpose weights to bf16 once.
// WT layout (ushort): [0) WqT 128x128 | [16384) WkT | [32768) WvT | [49152) W1T 128x256
// ---------------------------------------------------------------------------
__global__ __launch_bounds__(256) void prep_kernel(
    const float* __restrict__ Wq, const float* __restrict__ Wk,
    const float* __restrict__ Wv, const float* __restrict__ W1,
    ushort_t* __restrict__ WT)
{
    const int idx = blockIdx.x * 256 + threadIdx.x;
    if (idx < 16384) {
        int k = idx >> 7, n = idx & 127;
        WT[n * 128 + k] = f2bf(Wq[idx]);
    } else if (idx < 32768) {
        int i = idx - 16384; int k = i >> 7, n = i & 127;
        WT[16384 + n * 128 + k] = f2bf(Wk[i]);
    } else if (idx < 49152) {
        int i = idx - 32768; int k = i >> 7, n = i & 127;
        WT[32768 + n * 128 + k] = f2bf(Wv[i]);
    } else if (idx < 81920) {
        int i = idx - 49152; int k = i >> 7, n = i & 127;  // k in [0,256)
        WT[49152 + n * 256 + k] = f2bf(W1[i]);
    }
}

// ---------------------------------------------------------------------------
// Kernel A: Q = lrelu(E@Wq+bq) [f32 -> d_out], K,V -> interleaved KV [bf16].
// 128-row tiles (391 blocks), wave = 32 rows. A-frags loaded+converted ONCE,
// reused across 3 GEMMs. B staged in LDS (stride 136, conflict-free b128).
// ---------------------------------------------------------------------------
__global__ __launch_bounds__(256) void qkv_kernel(
    const float* __restrict__ E, const ushort_t* __restrict__ WT,
    const float* __restrict__ bq, const float* __restrict__ bk,
    const float* __restrict__ bv,
    float* __restrict__ Qo, ushort_t* __restrict__ KV)
{
    __shared__ ushort_t sW[128 * 136];

    const int tid  = threadIdx.x;
    const int wave = tid >> 6;
    const int lane = tid & 63;
    const int quad = lane >> 4;
    const int j    = lane & 15;
    const int row0 = blockIdx.x * 128 + wave * 32;

    const int ar0 = min(row0 + j,      N_NODES - 1);
    const int ar1 = min(row0 + 16 + j, N_NODES - 1);

    v8bf a0f[4], a1f[4];
#pragma unroll
    for (int ks = 0; ks < 4; ++ks) {
        const int k0 = ks * 32 + quad * 8;
        a0f[ks] = load8f(E + (size_t)ar0 * FDIM + k0);
        a1f[ks] = load8f(E + (size_t)ar1 * FDIM + k0);
    }

    const float* biases[3] = {bq, bk, bv};

    for (int w = 0; w < 3; ++w) {
        const ushort_t* Wsrc = WT + w * 16384;
        for (int i = tid; i < 2048; i += 256) {         // 16B copies
            int n = i >> 4, kc = i & 15;
            *(uint4*)(&sW[n * 136 + kc * 8]) = *(const uint4*)(Wsrc + n * 128 + kc * 8);
        }
        __syncthreads();

        v4f acc[2][8];
#pragma unroll
        for (int rb = 0; rb < 2; ++rb)
#pragma unroll
            for (int c = 0; c < 8; ++c) acc[rb][c] = (v4f){0.f, 0.f, 0.f, 0.f};

#pragma unroll
        for (int ks = 0; ks < 4; ++ks) {
            const int k0 = ks * 32 + quad * 8;
            v8bf b[8];
#pragma unroll
            for (int c = 0; c < 8; ++c)
                b[c] = *(const v8bf*)(&sW[(c * 16 + j) * 136 + k0]);
#pragma unroll
            for (int c = 0; c < 8; ++c) {
                acc[0][c] = __builtin_amdgcn_mfma_f32_16x16x32_bf16(a0f[ks], b[c], acc[0][c], 0, 0, 0);
                acc[1][c] = __builtin_amdgcn_mfma_f32_16x16x32_bf16(a1f[ks], b[c], acc[1][c], 0, 0, 0);
            }
        }

        const float* bias = biases[w];
#pragma unroll
        for (int c = 0; c < 8; ++c) {
            const int col = c * 16 + j;
            const float bv_ = bias[col];
#pragma unroll
            for (int rb = 0; rb < 2; ++rb) {
#pragma unroll
                for (int i = 0; i < 4; ++i) {
                    const int r = row0 + rb * 16 + quad * 4 + i;
                    if (r < N_NODES) {
                        const float x = lrelu(acc[rb][c][i] + bv_);
                        if (w == 0)      Qo[(size_t)r * HDIM + col] = x;
                        else if (w == 1) KV[(size_t)r * 256 + col] = f2bf(x);        // K half
                        else             KV[(size_t)r * 256 + 128 + col] = f2bf(x);  // V half
                    }
                }
            }
        }
        __syncthreads();
    }
}

// ---------------------------------------------------------------------------
// Kernel B: one wave per node, 4 nodes/block, 12500 blocks. TWO-PHASE:
// phase 1 pre-issues ALL 16 K gathers and ALL 16 V gathers into register
// arrays (32 concurrent 4B/lane loads in flight -> memory-level parallelism);
// phase 2 does the reductions/softmax/weighted-sum. Same per-neighbor
// arithmetic order as R3/R8 -> bit-identical output.
// Reads q (f32) from QP[node], overwrites the same row with pooled (f32).
// ---------------------------------------------------------------------------
__global__ __launch_bounds__(256) void attn_kernel(
    float* __restrict__ QP, const ushort_t* __restrict__ KV,
    const int* __restrict__ nbr)
{
    const int tid  = threadIdx.x;
    const int wave = tid >> 6;
    const int lane = tid & 63;
    const int node = __builtin_amdgcn_readfirstlane(blockIdx.x * 4 + wave);

    const float2 qp = ((const float2*)(QP + (size_t)node * HDIM))[lane];

    const int* nb = nbr + node * KNB;   // uniform base -> scalar loads
    int idxs[KNB];
#pragma unroll
    for (int t = 0; t < KNB; ++t) {
        int id = nb[t];
        idxs[t] = ((unsigned)id < (unsigned)N_NODES) ? id : 0;
    }

    // ---- phase 1: issue all 32 gathers (16 K rows + 16 V rows) ----
    unsigned int kp[KNB], vv[KNB];
#pragma unroll
    for (int t = 0; t < KNB; ++t)
        kp[t] = ((const unsigned int*)(KV + (size_t)idxs[t] * 256))[lane];
#pragma unroll
    for (int t = 0; t < KNB; ++t)
        vv[t] = ((const unsigned int*)(KV + (size_t)idxs[t] * 256 + 128))[lane];

    // ---- phase 2: score reductions (same order as R8) ----
    float sc[KNB];
#pragma unroll
    for (int t = 0; t < KNB; ++t) {
        float p = qp.x * blo(kp[t]) + qp.y * bhi(kp[t]);
#pragma unroll
        for (int off = 32; off >= 1; off >>= 1) p += __shfl_xor(p, off, 64);
        sc[t] = p;
    }

    float m = sc[0];
#pragma unroll
    for (int t = 1; t < KNB; ++t) m = fmaxf(m, sc[t]);
    float s = 0.f;
#pragma unroll
    for (int t = 0; t < KNB; ++t) { sc[t] = __expf(sc[t] - m); s += sc[t]; }
    const float inv = 1.f / s;

    float p0 = 0.f, p1 = 0.f;
#pragma unroll
    for (int t = 0; t < KNB; ++t) {
        const float a = sc[t] * inv;
        p0 += a * blo(vv[t]);
        p1 += a * bhi(vv[t]);
    }

    ((float2*)(QP + (size_t)node * HDIM))[lane] = make_float2(p0, p1);
}

// ---------------------------------------------------------------------------
// Kernel C (R4-proven aliasing): out = BN(rownorm(lrelu([E,pooled]@W1+b1))).
// pooled (f32) lives in d_out; result overwrites d_out. The barrier at the
// end of half=1 orders all pooled reads before any epilogue write within a
// block; blocks read/write only their own row range — no cross-block hazard.
// ---------------------------------------------------------------------------
__global__ __launch_bounds__(256) void out_kernel(
    const float* __restrict__ E, const ushort_t* __restrict__ W1T,
    const float* __restrict__ b1,
    const float* __restrict__ gamma, const float* __restrict__ beta,
    const float* __restrict__ mmean, const float* __restrict__ mvar,
    float* __restrict__ OutP)   // pooled (in) + out (result)
{
    __shared__ ushort_t sW[128 * 136];

    const int tid  = threadIdx.x;
    const int wave = tid >> 6;
    const int lane = tid & 63;
    const int quad = lane >> 4;
    const int j    = lane & 15;
    const int row0 = blockIdx.x * 128 + wave * 32;

    const int ar0 = min(row0 + j,      N_NODES - 1);
    const int ar1 = min(row0 + 16 + j, N_NODES - 1);

    v4f acc[2][8];
#pragma unroll
    for (int rb = 0; rb < 2; ++rb)
#pragma unroll
        for (int c = 0; c < 8; ++c) acc[rb][c] = (v4f){0.f, 0.f, 0.f, 0.f};

    for (int half = 0; half < 2; ++half) {
        for (int i = tid; i < 2048; i += 256) {
            int n = i >> 4, kc = i & 15;
            *(uint4*)(&sW[n * 136 + kc * 8]) =
                *(const uint4*)(W1T + n * 256 + half * 128 + kc * 8);
        }
        __syncthreads();

        const float* Abase = (half == 0) ? E : (const float*)OutP;
#pragma unroll
        for (int ks = 0; ks < 4; ++ks) {
            const int k0 = ks * 32 + quad * 8;
            v8bf a0 = load8f(Abase + (size_t)ar0 * 128 + k0);
            v8bf a1 = load8f(Abase + (size_t)ar1 * 128 + k0);
            v8bf b[8];
#pragma unroll
            for (int c = 0; c < 8; ++c)
                b[c] = *(const v8bf*)(&sW[(c * 16 + j) * 136 + k0]);
#pragma unroll
            for (int c = 0; c < 8; ++c) {
                acc[0][c] = __builtin_amdgcn_mfma_f32_16x16x32_bf16(a0, b[c], acc[0][c], 0, 0, 0);
                acc[1][c] = __builtin_amdgcn_mfma_f32_16x16x32_bf16(a1, b[c], acc[1][c], 0, 0, 0);
            }
        }
        __syncthreads();   // orders pooled reads before epilogue writes
    }

    float scale_[8], shift_[8], bias_[8];
#pragma unroll
    for (int c = 0; c < 8; ++c) {
        const int col = c * 16 + j;
        const float sc = gamma[col] * rsqrtf(mvar[col] + BN_EPS);
        scale_[c] = sc;
        shift_[c] = beta[col] - mmean[col] * sc;
        bias_[c]  = b1[col];
    }

#pragma unroll
    for (int rb = 0; rb < 2; ++rb)
#pragma unroll
        for (int c = 0; c < 8; ++c)
#pragma unroll
            for (int i = 0; i < 4; ++i)
                acc[rb][c][i] = lrelu(acc[rb][c][i] + bias_[c]);

#pragma unroll
    for (int rb = 0; rb < 2; ++rb) {
#pragma unroll
        for (int i = 0; i < 4; ++i) {
            float ss = 0.f;
#pragma unroll
            for (int c = 0; c < 8; ++c) ss += acc[rb][c][i] * acc[rb][c][i];
            ss += __shfl_xor(ss, 1, 64);
            ss += __shfl_xor(ss, 2, 64);
            ss += __shfl_xor(ss, 4, 64);
            ss += __shfl_xor(ss, 8, 64);
            const float invn = 1.f / (sqrtf(ss) + 1e-6f);
            const int r = row0 + rb * 16 + quad * 4 + i;
            if (r < N_NODES) {
#pragma unroll
                for (int c = 0; c < 8; ++c)
                    OutP[(size_t)r * HDIM + c * 16 + j] =
                        acc[rb][c][i] * invn * scale_[c] + shift_[c];
            }
        }
    }
}

extern "C" void kernel_launch(void* const* d_in, const int* in_sizes, int n_in,
                              void* d_out, int out_size, void* d_ws, size_t ws_size,
                              hipStream_t stream)
{
    const float* E     = (const float*)d_in[0];
    const int*   nbr   = (const int*)d_in[2];
    const float* Wq    = (const float*)d_in[3];
    const float* bq    = (const float*)d_in[4];
    const float* Wk    = (const float*)d_in[5];
    const float* bk    = (const float*)d_in[6];
    const float* Wv    = (const float*)d_in[7];
    const float* bv    = (const float*)d_in[8];
    const float* W1    = (const float*)d_in[9];
    const float* b1    = (const float*)d_in[10];
    const float* gam   = (const float*)d_in[11];
    const float* bet   = (const float*)d_in[12];
    const float* mmean = (const float*)d_in[13];
    const float* mvar  = (const float*)d_in[14];

    // ws: KV interleaved bf16 (25.6 MB) + WT bf16 (160 KB) = 25.76 MB total
    // (PROVEN budget — 38.56 MB overflowed d_ws in R7). Q (f32) then pooled
    // (f32) share d_out.
    ushort_t* KV = (ushort_t*)d_ws;
    ushort_t* WT = KV + (size_t)N_NODES * 256;
    float* QP = (float*)d_out;

    const int gridA = (N_NODES + 127) / 128;  // 391
    prep_kernel<<<320, 256, 0, stream>>>(Wq, Wk, Wv, W1, WT);
    qkv_kernel<<<gridA, 256, 0, stream>>>(E, WT, bq, bk, bv, QP, KV);
    attn_kernel<<<N_NODES / 4, 256, 0, stream>>>(QP, KV, nbr);
    out_kernel<<<gridA, 256, 0, stream>>>(E, WT + 49152, b1, gam, bet, mmean, mvar, QP);
}